// Round 9
// baseline (1062.153 us; speedup 1.0000x reference)
//
#include <hip/hip_runtime.h>
#include <hip/hip_bf16.h>

#define NB   16      // batch
#define FDIM 2048    // lstm hidden
#define GDIM 8192    // 4*FDIM gates
#define WSEQ 32      // seq len
#define CDIM 256
#define CBD  64
#define HGT  32

#define PSTR 18        // part[] stride (2-way bank aliasing = free)
#define BARSTRIDE 544  // u32 per stage: 16 group lines + 1 root line, 128B apart
#define AGENTSC __HIP_MEMORY_SCOPE_AGENT

typedef float f32x4 __attribute__((ext_vector_type(4)));
typedef long  l64x2 __attribute__((ext_vector_type(2)));
typedef unsigned char u8;

__device__ __forceinline__ float sigf(float x) { return 1.f / (1.f + __expf(-x)); }

__device__ __forceinline__ u8 f32_to_fp8(float f) {
    int w = __builtin_amdgcn_cvt_pk_fp8_f32(f, f, 0, 0);
    return (u8)(w & 0xff);
}

// ---------------------------------------------------------------------------
// Coalesced weight pack -> fp8 e4m3 (layout as R5-R8), 4 rows in flight.
// ---------------------------------------------------------------------------
__global__ __launch_bounds__(256) void pack_w(
        const float* __restrict__ wih0, const float* __restrict__ whh0,
        const float* __restrict__ wih1, const float* __restrict__ whh1,
        u8* __restrict__ W0, u8* __restrict__ W1) {
    __shared__ u8 FW[16][4112];   // [c][k], +16 pad
    int b = blockIdx.x;           // 0..1023
    int mat = b >> 9, tile = b & 511;
    const float* wih = mat ? wih1 : wih0;
    const float* whh = mat ? whh1 : whh0;
    int p = tile & 1, jt = tile >> 1;
    int tid = threadIdx.x;
    for (int it = 0; it < 32; it += 4) {   // 2 src halves x 16 rows, 4-deep ILP
        float4 f[4][2];
#pragma unroll
        for (int r = 0; r < 4; ++r) {
            int c = (it + r) & 15, srcsel = (it + r) >> 4;
            int gate = p * 2 + (c >> 3);
            int rr = gate * FDIM + jt * 8 + (c & 7);
            const float* s = (srcsel ? whh : wih) + (size_t)rr * FDIM + tid * 8;
            f[r][0] = *(const float4*)(s);
            f[r][1] = *(const float4*)(s + 4);
        }
#pragma unroll
        for (int r = 0; r < 4; ++r) {
            int c = (it + r) & 15, srcsel = (it + r) >> 4;
            int w0 = __builtin_amdgcn_cvt_pk_fp8_f32(f[r][0].x, f[r][0].y, 0, 0);
            w0     = __builtin_amdgcn_cvt_pk_fp8_f32(f[r][0].z, f[r][0].w, w0, 1);
            int w1 = __builtin_amdgcn_cvt_pk_fp8_f32(f[r][1].x, f[r][1].y, 0, 0);
            w1     = __builtin_amdgcn_cvt_pk_fp8_f32(f[r][1].z, f[r][1].w, w1, 1);
            *(int2*)&FW[c][srcsel * 2048 + tid * 8] = make_int2(w0, w1);
        }
    }
    __syncthreads();
    u8* base = (mat ? W1 : W0) + (size_t)tile * 65536;
#pragma unroll
    for (int w = 0; w < 16; ++w) {
        int q = w * 256 + tid;            // kc2*64 + lane
        int kc2 = q >> 6, lane = q & 63;
        int c = lane & 15, kg = lane >> 4;
        l64x2 v;
        v.x = *(const long*)&FW[c][kc2 * 64 + kg * 8];
        v.y = *(const long*)&FW[c][kc2 * 64 + 32 + kg * 8];
        *(l64x2*)(base + (size_t)q * 16) = v;
    }
}

__global__ void bias_k(const float* __restrict__ bih0, const float* __restrict__ bhh0,
                       const float* __restrict__ bih1, const float* __restrict__ bhh1,
                       float* __restrict__ b0, float* __restrict__ b1) {
    int i = blockIdx.x * blockDim.x + threadIdx.x;
    if (i < GDIM)            b0[i] = bih0[i] + bhh0[i];
    else if (i < 2 * GDIM) { int j = i - GDIM; b1[j] = bih1[j] + bhh1[j]; }
}

// ---------------------------------------------------------------------------
// 1x1 conv-in; emit seq in PACKED A-fragment layout:
//   seqbP[t] : [64 kc][64 lane][8B], byte i of (kc,lane): k = kc*32+(lane>>4)*8+i
// ---------------------------------------------------------------------------
__global__ __launch_bounds__(256) void conv_in(const float* __restrict__ latent,
                        const float* __restrict__ w_in, const float* __restrict__ b_in,
                        u8* __restrict__ seqbP) {
    __shared__ float lat[CDIM * HGT]; // [c][h] 32 KiB
    __shared__ float hv[FDIM];        // 8 KiB
    int b = blockIdx.x; int n = b >> 5; int t = b & 31;
    int tid = threadIdx.x;
    for (int i = 0; i < 32; ++i) {
        int flat = i * 256 + tid;         // c*32+h
        int c = flat >> 5, h = flat & 31;
        lat[flat] = latent[(((size_t)n * CDIM + c) * WSEQ + t) * HGT + h];
    }
    __syncthreads();
    int cb = tid & 63;
    int hb = tid >> 6;
    float acc[8];
#pragma unroll
    for (int k = 0; k < 8; ++k) acc[k] = b_in[cb];
    for (int c = 0; c < CDIM; ++c) {
        float wv = w_in[cb * CDIM + c];
#pragma unroll
        for (int k = 0; k < 8; ++k) acc[k] += lat[c * HGT + (hb + k * 4)] * wv;
    }
#pragma unroll
    for (int k = 0; k < 8; ++k) hv[k * 256 + tid] = acc[k];   // hv[f], f = h*64+cb
    __syncthreads();
    union { u8 by[8]; long l; } pk;
#pragma unroll
    for (int i = 0; i < 8; ++i) pk.by[i] = f32_to_fp8(hv[tid * 8 + i]);
    *(long*)(seqbP + (size_t)t * 32768 + (tid >> 2) * 512 + (tid & 3) * 128 + n * 8) = pk.l;
}

// ---------------------------------------------------------------------------
// Async load cluster: 8 independent NORMAL (L2-cached) 8B loads, no waits.
// Coherence: consumers run after grid_bar's acquire-fence (L1+L2 inv), and
// producers store with sc1 -> L2 never holds stale or dirty activation lines.
// Caller MUST call vm_wait0() before consuming f[].
// ---------------------------------------------------------------------------
__device__ __forceinline__ void loadA8_async(const u8* base, long* f) {
#pragma unroll
    for (int i = 0; i < 8; ++i) {
        const u8* p = base + (size_t)i * 512;
        asm volatile("global_load_dwordx2 %0, %1, off" : "=v"(f[i]) : "v"(p));
    }
}

__device__ __forceinline__ void vm_wait0() {
    asm volatile("s_waitcnt vmcnt(0)" ::: "memory");
    __builtin_amdgcn_sched_barrier(0);   // keep MFMAs from hoisting above the wait
}

__device__ __forceinline__ f32x4 mfma8(long a, long b, f32x4 acc) {
    return __builtin_amdgcn_mfma_f32_16x16x32_fp8_fp8(a, b, acc, 0, 0, 0);
}

__device__ __forceinline__ void mma8r(const long* f, const l64x2* b, f32x4& a0, f32x4& a1) {
#pragma unroll
    for (int i = 0; i < 4; ++i) {
        a0 = mfma8(f[2 * i],     b[i].x, a0);
        a1 = mfma8(f[2 * i + 1], b[i].y, a1);
    }
}

__device__ __forceinline__ void mma8l(const long* f, const l64x2* bb, f32x4& a0, f32x4& a1) {
#pragma unroll
    for (int i = 0; i < 4; ++i) {
        l64x2 bl = bb[(size_t)i * 64];
        a0 = mfma8(f[2 * i],     bl.x, a0);
        a1 = mfma8(f[2 * i + 1], bl.y, a1);
    }
}

__device__ __forceinline__ void store_part(float* part, int wave, int kg, int la, f32x4 acc) {
#pragma unroll
    for (int q = 0; q < 4; ++q) part[(wave * 16 + kg * 4 + q) * PSTR + la] = acc[q];
}

// LSTM cell tail: c-state and biases in registers; ALL global stores sc1.
__device__ __forceinline__ void cell_tail(int jt, int tid, const float* part,
        float bi, float bf, float bg, float bo, float& cr,
        u8* hA, u8* hB, float* seqSlot) {
    if (tid < 128) {
        int m = tid >> 3, jj = tid & 7;
        float gi = 0.f, gf = 0.f, gg = 0.f, go = 0.f;
#pragma unroll
        for (int e = 0; e < 8; ++e) {
            gi += part[(e * 16 + m) * PSTR + jj];
            gf += part[(e * 16 + m) * PSTR + 8 + jj];
            gg += part[((8 + e) * 16 + m) * PSTR + jj];
            go += part[((8 + e) * 16 + m) * PSTR + 8 + jj];
        }
        float cn = sigf(gf + bf) * cr + sigf(gi + bi) * tanhf(gg + bg);
        float h  = sigf(go + bo) * tanhf(cn);
        cr = cn;
        u8 hb = f32_to_fp8(h);
        int pos = (jt >> 2) * 512 + (jt & 3) * 128 + tid;
        __hip_atomic_store(hA + 32768 + pos, hb, __ATOMIC_RELAXED, AGENTSC);
        __hip_atomic_store(hB + pos,         hb, __ATOMIC_RELAXED, AGENTSC);
        if (seqSlot) {
            int j = jt * 8 + jj;
            __hip_atomic_store(seqSlot + m * FDIM + j, h, __ATOMIC_RELAXED, AGENTSC);
        }
    }
}

// Grid barrier: 16 groups x 16 + root, 128B-isolated, fresh slots per stage.
// Arrival: RELEASE RMW (drains producer's sc1 stores). After poll success,
// ONE acquire-agent fence per block (s_waitcnt + L1/L2 inv) so the following
// NORMAL activation loads refetch fresh lines L3 -> L2 (shared per-XCD).
__device__ __forceinline__ void grid_bar(unsigned* base) {
    __syncthreads();
    if (threadIdx.x == 0) {
        unsigned* loc  = base + (blockIdx.x & 15) * 32;
        unsigned* root = base + 512;
        unsigned prev = __hip_atomic_fetch_add(loc, 1u, __ATOMIC_RELEASE, AGENTSC);
        if (prev == 15u)
            __hip_atomic_fetch_add(root, 1u, __ATOMIC_RELEASE, AGENTSC);
        int guard = 0;
        while (__hip_atomic_load(root, __ATOMIC_RELAXED, AGENTSC) < 16u
               && ++guard < (1 << 24))
            __builtin_amdgcn_s_sleep(1);
        __builtin_amdgcn_fence(__ATOMIC_ACQUIRE, "agent");  // one L1+L2 inv per CU per stage
    }
    __syncthreads();
}

// ---------------------------------------------------------------------------
// Persistent recurrence. 256 blocks x 1024 thr (1 block/CU). Block jt owns
// features jt*8..jt*8+7 for all 4 gates. W1 slice (128 KiB) in LDS; W0 slice
// (128 KiB) pinned in registers; c-state + biases in registers. Activation
// loads NORMAL (per-XCD L2-shared); h stores sc1; coherence via per-stage
// acquire fence in grid_bar.
// ---------------------------------------------------------------------------
__global__ __launch_bounds__(1024, 4) void recurrence(
        const u8* __restrict__ W0, const u8* __restrict__ W1,
        const u8* __restrict__ seqbP,
        const float* __restrict__ b0, const float* __restrict__ b1,
        u8* __restrict__ a00, u8* __restrict__ a01,
        u8* __restrict__ a10, u8* __restrict__ a11,
        float* __restrict__ sqo, unsigned* __restrict__ bar) {
    __shared__ uint4 w1lds[8192];          // 128 KiB W1 slice
    __shared__ float part[16 * 16 * PSTR]; // 18.4 KiB
    const int jt = blockIdx.x, tid = threadIdx.x;
    const int wave = tid >> 6, l = tid & 63;
    const int gp = wave >> 3, ke = wave & 7;   // gate-pair, k-eighth
    const int la = l & 15, kg = l >> 4;
    const int tIdx = jt * 2 + gp;
    {
        const uint4* src = (const uint4*)(W1 + (size_t)jt * 131072);
        for (int i = tid; i < 8192; i += 1024) w1lds[i] = src[i];
    }
    // pin this wave's W0 fragments: kc2 = ke*8 .. ke*8+7
    l64x2 b0pin[8];
    {
        const u8* Bb = W0 + ((size_t)(tIdx * 64 + ke * 8) * 64 + l) * 16;
#pragma unroll
        for (int i = 0; i < 8; ++i) b0pin[i] = *(const l64x2*)(Bb + (size_t)i * 1024);
    }
    // registers: cell state + biases
    float cr0 = 0.f, cr1 = 0.f;
    float bi0 = 0, bf0 = 0, bg0 = 0, bo0 = 0, bi1 = 0, bf1 = 0, bg1 = 0, bo1 = 0;
    if (tid < 128) {
        int j = jt * 8 + (tid & 7);
        bi0 = b0[j]; bf0 = b0[FDIM + j]; bg0 = b0[2 * FDIM + j]; bo0 = b0[3 * FDIM + j];
        bi1 = b1[j]; bf1 = b1[FDIM + j]; bg1 = b1[2 * FDIM + j]; bo1 = b1[3 * FDIM + j];
    }
    __syncthreads();

    u8* a0arr[2] = {a00, a01};
    u8* a1arr[2] = {a10, a11};
    unsigned* bs = bar;
    const l64x2* bb1 = (const l64x2*)w1lds + ((size_t)(gp * 64 + ke * 8) * 64 + l);
    const f32x4 z = {0.f, 0.f, 0.f, 0.f};

    auto l0_phase = [&](const u8* xsrc, const u8* A0, u8* hA, u8* hB) {
        long fa[8], fb[8];
        const u8* base = ((ke < 4) ? xsrc : A0) + (size_t)(ke * 16) * 512 + (size_t)l * 8;
        loadA8_async(base, fa); loadA8_async(base + 4096, fb);
        vm_wait0();
        f32x4 qa = z, qb = z;
        mma8r(fa, b0pin, qa, qb);
        mma8r(fb, b0pin + 4, qa, qb);
        store_part(part, wave, kg, la, qa + qb);
        __syncthreads();
        cell_tail(jt, tid, part, bi0, bf0, bg0, bo0, cr0, hA, hB, nullptr);
    };
    auto l1_phase = [&](const u8* A1, u8* hA, u8* hB, float* slot) {
        long fa[8], fb[8];
        const u8* base = A1 + (size_t)(ke * 16) * 512 + (size_t)l * 8;
        loadA8_async(base, fa); loadA8_async(base + 4096, fb);
        vm_wait0();
        f32x4 qa = z, qb = z;
        mma8l(fa, bb1, qa, qb);
        mma8l(fb, bb1 + 4 * 64, qa, qb);
        store_part(part, wave, kg, la, qa + qb);
        __syncthreads();
        cell_tail(jt, tid, part, bi1, bf1, bg1, bo1, cr1, hA, hB, slot);
    };

    // stage 0: L0[0] (h-half zeros)
    l0_phase(seqbP, a00, a01, a10);
    grid_bar(bs); bs += BARSTRIDE;

    // fwd stages s=0..30: L0[s+1] + L1[s]; all 32 loads issued as ONE cluster
    for (int s = 0; s <= 30; ++s) {
        int bp = s & 1;
        const u8* A0 = a0arr[1 - bp];
        const u8* xs = seqbP + (size_t)(s + 1) * 32768;
        const u8* A1 = a1arr[bp];
        long f0a[8], f0b[8], f1a[8], f1b[8];
        const u8* base0 = ((ke < 4) ? xs : A0) + (size_t)(ke * 16) * 512 + (size_t)l * 8;
        const u8* base1 = A1 + (size_t)(ke * 16) * 512 + (size_t)l * 8;
        loadA8_async(base0, f0a); loadA8_async(base0 + 4096, f0b);
        loadA8_async(base1, f1a); loadA8_async(base1 + 4096, f1b);
        vm_wait0();
        f32x4 q0a = z, q0b = z, q1a = z, q1b = z;
        mma8r(f0a, b0pin, q0a, q0b);
        mma8r(f0b, b0pin + 4, q0a, q0b);
        mma8l(f1a, bb1, q1a, q1b);
        mma8l(f1b, bb1 + 4 * 64, q1a, q1b);
        store_part(part, wave, kg, la, q0a + q0b);
        __syncthreads();
        cell_tail(jt, tid, part, bi0, bf0, bg0, bo0, cr0, a0arr[bp], a1arr[1 - bp], nullptr);
        __syncthreads();
        store_part(part, wave, kg, la, q1a + q1b);
        __syncthreads();
        cell_tail(jt, tid, part, bi1, bf1, bg1, bo1, cr1, a1arr[1 - bp], a0arr[1 - bp], nullptr);
        grid_bar(bs); bs += BARSTRIDE;
    }
    // stage: L1[31] -> first recorded output
    l1_phase(a1arr[1], a1arr[0], a0arr[0], sqo);
    grid_bar(bs); bs += BARSTRIDE;
    // AR region s=32..62
    for (int s = 32; s < 63; ++s) {
        int bp = s & 1;
        l0_phase(a0arr[bp], a0arr[bp], a0arr[1 - bp], a1arr[bp]);
        grid_bar(bs); bs += BARSTRIDE;
        l1_phase(a1arr[bp], a1arr[1 - bp], a0arr[1 - bp],
                 sqo + (size_t)(s - 31) * NB * FDIM);
        if (s != 62) { grid_bar(bs); bs += BARSTRIDE; }
    }
}

// copy latent -> out[:, :, 0:32, :]
__global__ void copy_lat(const float* __restrict__ latent, float* __restrict__ out) {
    size_t i = (size_t)blockIdx.x * blockDim.x + threadIdx.x;
    if (i >= (size_t)1048576) return;
    size_t blk = i >> 8;
    size_t within = i & 255;
    float4 v = ((const float4*)latent)[i];
    ((float4*)out)[blk * 512 + within] = v;
}

// gen half: out[n][c][32+t][h] = sum_cb seq_out[t][n][h*64+cb]*w_out[c][cb] + b_out[c]
__global__ __launch_bounds__(256) void gen_out(const float* __restrict__ seq_out,
                        const float* __restrict__ w_out, const float* __restrict__ b_out,
                        float* __restrict__ out) {
    __shared__ float row[32 * 65];
    int b = blockIdx.x; int n = b >> 5, t = b & 31;
    const float* src = seq_out + ((size_t)t * NB + n) * FDIM;
    for (int i = threadIdx.x; i < FDIM; i += 256)
        row[(i >> 6) * 65 + (i & 63)] = src[i];
    __syncthreads();
    for (int it = 0; it < 32; ++it) {
        int o = it * 256 + threadIdx.x;
        int c = o >> 5, h = o & 31;
        float acc = b_out[c];
#pragma unroll
        for (int cb = 0; cb < CBD; ++cb) acc += row[h * 65 + cb] * w_out[c * CBD + cb];
        out[(((size_t)n * CDIM + c) * 64 + 32 + t) * HGT + h] = acc;
    }
}

extern "C" void kernel_launch(void* const* d_in, const int* in_sizes, int n_in,
                              void* d_out, int out_size, void* d_ws, size_t ws_size,
                              hipStream_t stream) {
    const float* latent = (const float*)d_in[0];
    const float* w_in   = (const float*)d_in[1];
    const float* b_in   = (const float*)d_in[2];
    const float* w_ih0  = (const float*)d_in[3];
    const float* w_hh0  = (const float*)d_in[4];
    const float* b_ih0  = (const float*)d_in[5];
    const float* b_hh0  = (const float*)d_in[6];
    const float* w_ih1  = (const float*)d_in[7];
    const float* w_hh1  = (const float*)d_in[8];
    const float* b_ih1  = (const float*)d_in[9];
    const float* b_hh1  = (const float*)d_in[10];
    const float* w_out  = (const float*)d_in[11];
    const float* b_out  = (const float*)d_in[12];
    float* out = (float*)d_out;
    char* ws = (char*)d_ws;

    size_t off = 0;
    u8*    W0   = (u8*)(ws + off); off += (size_t)512 * 65536;             // 32 MiB
    u8*    W1   = (u8*)(ws + off); off += (size_t)512 * 65536;             // 32 MiB
    u8*    seqbP= (u8*)(ws + off); off += (size_t)WSEQ * 32768;            // 1 MiB
    float* sqo  = (float*)(ws + off); off += (size_t)WSEQ * NB * FDIM * 4; // 4 MiB
    char*  zbase = ws + off;
    u8* a00 = (u8*)(ws + off); off += 65536;
    u8* a01 = (u8*)(ws + off); off += 65536;
    u8* a10 = (u8*)(ws + off); off += 65536;
    u8* a11 = (u8*)(ws + off); off += 65536;
    unsigned* bar = (unsigned*)(ws + off); off += (size_t)96 * BARSTRIDE * 4; // 204 KiB
    size_t zbytes = (size_t)(ws + off - zbase);
    float* b0 = (float*)(ws + off); off += (size_t)GDIM * 4;
    float* b1 = (float*)(ws + off); off += (size_t)GDIM * 4;

    if (ws_size < off) {
        hipMemsetAsync(d_out, 0, (size_t)out_size * 4, stream);
        return;
    }

    hipMemsetAsync(zbase, 0, zbytes, stream);
    pack_w<<<1024, 256, 0, stream>>>(w_ih0, w_hh0, w_ih1, w_hh1, W0, W1);
    bias_k<<<64, 256, 0, stream>>>(b_ih0, b_hh0, b_ih1, b_hh1, b0, b1);
    conv_in<<<512, 256, 0, stream>>>(latent, w_in, b_in, seqbP);
    recurrence<<<256, 1024, 0, stream>>>(W0, W1, seqbP, b0, b1,
                                         a00, a01, a10, a11, sqo, bar);
    copy_lat<<<4096, 256, 0, stream>>>(latent, out);
    gen_out<<<512, 256, 0, stream>>>(sqo, w_out, b_out, out);
}

// Round 10
// 1057.129 us; speedup vs baseline: 1.0048x; 1.0048x over previous
//
#include <hip/hip_runtime.h>
#include <hip/hip_bf16.h>

#define NB   16      // batch
#define FDIM 2048    // lstm hidden
#define GDIM 8192    // 4*FDIM gates
#define WSEQ 32      // seq len
#define CDIM 256
#define CBD  64
#define HGT  32

#define PSTR 18        // part[] stride (2-way bank aliasing = free)
#define BARSTRIDE 544  // u32 per stage: 16 group lines + 1 root line, 128B apart
#define AGENTSC __HIP_MEMORY_SCOPE_AGENT

typedef float f32x4 __attribute__((ext_vector_type(4)));
typedef long  l64x2 __attribute__((ext_vector_type(2)));
typedef unsigned char u8;

__device__ __forceinline__ float sigf(float x) { return 1.f / (1.f + __expf(-x)); }

__device__ __forceinline__ u8 f32_to_fp8(float f) {
    int w = __builtin_amdgcn_cvt_pk_fp8_f32(f, f, 0, 0);
    return (u8)(w & 0xff);
}

// ---------------------------------------------------------------------------
// Coalesced weight pack -> fp8 e4m3 (layout as R5-R8), 4 rows in flight.
// ---------------------------------------------------------------------------
__global__ __launch_bounds__(256) void pack_w(
        const float* __restrict__ wih0, const float* __restrict__ whh0,
        const float* __restrict__ wih1, const float* __restrict__ whh1,
        u8* __restrict__ W0, u8* __restrict__ W1) {
    __shared__ u8 FW[16][4112];   // [c][k], +16 pad
    int b = blockIdx.x;           // 0..1023
    int mat = b >> 9, tile = b & 511;
    const float* wih = mat ? wih1 : wih0;
    const float* whh = mat ? whh1 : whh0;
    int p = tile & 1, jt = tile >> 1;
    int tid = threadIdx.x;
    for (int it = 0; it < 32; it += 4) {   // 2 src halves x 16 rows, 4-deep ILP
        float4 f[4][2];
#pragma unroll
        for (int r = 0; r < 4; ++r) {
            int c = (it + r) & 15, srcsel = (it + r) >> 4;
            int gate = p * 2 + (c >> 3);
            int rr = gate * FDIM + jt * 8 + (c & 7);
            const float* s = (srcsel ? whh : wih) + (size_t)rr * FDIM + tid * 8;
            f[r][0] = *(const float4*)(s);
            f[r][1] = *(const float4*)(s + 4);
        }
#pragma unroll
        for (int r = 0; r < 4; ++r) {
            int c = (it + r) & 15, srcsel = (it + r) >> 4;
            int w0 = __builtin_amdgcn_cvt_pk_fp8_f32(f[r][0].x, f[r][0].y, 0, 0);
            w0     = __builtin_amdgcn_cvt_pk_fp8_f32(f[r][0].z, f[r][0].w, w0, 1);
            int w1 = __builtin_amdgcn_cvt_pk_fp8_f32(f[r][1].x, f[r][1].y, 0, 0);
            w1     = __builtin_amdgcn_cvt_pk_fp8_f32(f[r][1].z, f[r][1].w, w1, 1);
            *(int2*)&FW[c][srcsel * 2048 + tid * 8] = make_int2(w0, w1);
        }
    }
    __syncthreads();
    u8* base = (mat ? W1 : W0) + (size_t)tile * 65536;
#pragma unroll
    for (int w = 0; w < 16; ++w) {
        int q = w * 256 + tid;            // kc2*64 + lane
        int kc2 = q >> 6, lane = q & 63;
        int c = lane & 15, kg = lane >> 4;
        l64x2 v;
        v.x = *(const long*)&FW[c][kc2 * 64 + kg * 8];
        v.y = *(const long*)&FW[c][kc2 * 64 + 32 + kg * 8];
        *(l64x2*)(base + (size_t)q * 16) = v;
    }
}

__global__ void bias_k(const float* __restrict__ bih0, const float* __restrict__ bhh0,
                       const float* __restrict__ bih1, const float* __restrict__ bhh1,
                       float* __restrict__ b0, float* __restrict__ b1) {
    int i = blockIdx.x * blockDim.x + threadIdx.x;
    if (i < GDIM)            b0[i] = bih0[i] + bhh0[i];
    else if (i < 2 * GDIM) { int j = i - GDIM; b1[j] = bih1[j] + bhh1[j]; }
}

// ---------------------------------------------------------------------------
// 1x1 conv-in; emit seq in PACKED A-fragment layout:
//   seqbP[t] : [64 kc][64 lane][8B], byte i of (kc,lane): k = kc*32+(lane>>4)*8+i
// ---------------------------------------------------------------------------
__global__ __launch_bounds__(256) void conv_in(const float* __restrict__ latent,
                        const float* __restrict__ w_in, const float* __restrict__ b_in,
                        u8* __restrict__ seqbP) {
    __shared__ float lat[CDIM * HGT]; // [c][h] 32 KiB
    __shared__ float hv[FDIM];        // 8 KiB
    int b = blockIdx.x; int n = b >> 5; int t = b & 31;
    int tid = threadIdx.x;
    for (int i = 0; i < 32; ++i) {
        int flat = i * 256 + tid;         // c*32+h
        int c = flat >> 5, h = flat & 31;
        lat[flat] = latent[(((size_t)n * CDIM + c) * WSEQ + t) * HGT + h];
    }
    __syncthreads();
    int cb = tid & 63;
    int hb = tid >> 6;
    float acc[8];
#pragma unroll
    for (int k = 0; k < 8; ++k) acc[k] = b_in[cb];
    for (int c = 0; c < CDIM; ++c) {
        float wv = w_in[cb * CDIM + c];
#pragma unroll
        for (int k = 0; k < 8; ++k) acc[k] += lat[c * HGT + (hb + k * 4)] * wv;
    }
#pragma unroll
    for (int k = 0; k < 8; ++k) hv[k * 256 + tid] = acc[k];   // hv[f], f = h*64+cb
    __syncthreads();
    union { u8 by[8]; long l; } pk;
#pragma unroll
    for (int i = 0; i < 8; ++i) pk.by[i] = f32_to_fp8(hv[tid * 8 + i]);
    *(long*)(seqbP + (size_t)t * 32768 + (tid >> 2) * 512 + (tid & 3) * 128 + n * 8) = pk.l;
}

// ---------------------------------------------------------------------------
// Async load cluster: 8 independent NORMAL (L2-cached) 8B loads, no waits.
// Coherence: consumers run after grid_bar's acquire-fence (L1+L2 inv), and
// producers store with sc1 -> L2 never holds stale or dirty activation lines.
// Caller MUST call vm_wait0() before consuming f[].
// ---------------------------------------------------------------------------
__device__ __forceinline__ void loadA8_async(const u8* base, long* f) {
#pragma unroll
    for (int i = 0; i < 8; ++i) {
        const u8* p = base + (size_t)i * 512;
        asm volatile("global_load_dwordx2 %0, %1, off" : "=v"(f[i]) : "v"(p));
    }
}

__device__ __forceinline__ void vm_wait0() {
    asm volatile("s_waitcnt vmcnt(0)" ::: "memory");
    __builtin_amdgcn_sched_barrier(0);   // keep MFMAs from hoisting above the wait
}

__device__ __forceinline__ f32x4 mfma8(long a, long b, f32x4 acc) {
    return __builtin_amdgcn_mfma_f32_16x16x32_fp8_fp8(a, b, acc, 0, 0, 0);
}

__device__ __forceinline__ void mma8r(const long* f, const l64x2* b, f32x4& a0, f32x4& a1) {
#pragma unroll
    for (int i = 0; i < 4; ++i) {
        a0 = mfma8(f[2 * i],     b[i].x, a0);
        a1 = mfma8(f[2 * i + 1], b[i].y, a1);
    }
}

__device__ __forceinline__ void mma8l(const long* f, const l64x2* bb, f32x4& a0, f32x4& a1) {
#pragma unroll
    for (int i = 0; i < 4; ++i) {
        l64x2 bl = bb[(size_t)i * 64];
        a0 = mfma8(f[2 * i],     bl.x, a0);
        a1 = mfma8(f[2 * i + 1], bl.y, a1);
    }
}

__device__ __forceinline__ void store_part(float* part, int wave, int kg, int la, f32x4 acc) {
#pragma unroll
    for (int q = 0; q < 4; ++q) part[(wave * 16 + kg * 4 + q) * PSTR + la] = acc[q];
}

// LSTM cell tail: c-state and biases in registers; ALL global stores sc1.
__device__ __forceinline__ void cell_tail(int jt, int tid, const float* part,
        float bi, float bf, float bg, float bo, float& cr,
        u8* hA, u8* hB, float* seqSlot) {
    if (tid < 128) {
        int m = tid >> 3, jj = tid & 7;
        float gi = 0.f, gf = 0.f, gg = 0.f, go = 0.f;
#pragma unroll
        for (int e = 0; e < 8; ++e) {
            gi += part[(e * 16 + m) * PSTR + jj];
            gf += part[(e * 16 + m) * PSTR + 8 + jj];
            gg += part[((8 + e) * 16 + m) * PSTR + jj];
            go += part[((8 + e) * 16 + m) * PSTR + 8 + jj];
        }
        float cn = sigf(gf + bf) * cr + sigf(gi + bi) * tanhf(gg + bg);
        float h  = sigf(go + bo) * tanhf(cn);
        cr = cn;
        u8 hb = f32_to_fp8(h);
        int pos = (jt >> 2) * 512 + (jt & 3) * 128 + tid;
        __hip_atomic_store(hA + 32768 + pos, hb, __ATOMIC_RELAXED, AGENTSC);
        __hip_atomic_store(hB + pos,         hb, __ATOMIC_RELAXED, AGENTSC);
        if (seqSlot) {
            int j = jt * 8 + jj;
            __hip_atomic_store(seqSlot + m * FDIM + j, h, __ATOMIC_RELAXED, AGENTSC);
        }
    }
}

// Grid barrier: 16 groups x 16 + root, 128B-isolated, fresh slots per stage.
// Arrival: RELEASE RMW (drains producer's sc1 stores). After poll success,
// ONE acquire-agent fence per block (s_waitcnt + L1/L2 inv) so the following
// NORMAL activation loads refetch fresh lines L3 -> L2 (shared per-XCD).
__device__ __forceinline__ void grid_bar(unsigned* base) {
    __syncthreads();
    if (threadIdx.x == 0) {
        unsigned* loc  = base + (blockIdx.x & 15) * 32;
        unsigned* root = base + 512;
        unsigned prev = __hip_atomic_fetch_add(loc, 1u, __ATOMIC_RELEASE, AGENTSC);
        if (prev == 15u)
            __hip_atomic_fetch_add(root, 1u, __ATOMIC_RELEASE, AGENTSC);
        int guard = 0;
        while (__hip_atomic_load(root, __ATOMIC_RELAXED, AGENTSC) < 16u
               && ++guard < (1 << 24))
            __builtin_amdgcn_s_sleep(1);
        __builtin_amdgcn_fence(__ATOMIC_ACQUIRE, "agent");  // one L1+L2 inv per CU per stage
    }
    __syncthreads();
}

// ---------------------------------------------------------------------------
// Persistent recurrence. 256 blocks x 1024 thr (1 block/CU). Block jt owns
// features jt*8..jt*8+7 for all 4 gates. W1 slice (128 KiB) in LDS; W0 slice
// (128 KiB) pinned in registers; c-state + biases in registers. Activation
// loads NORMAL (per-XCD L2-shared); h stores sc1; coherence via per-stage
// acquire fence in grid_bar.
// ---------------------------------------------------------------------------
__global__ __launch_bounds__(1024, 4) void recurrence(
        const u8* __restrict__ W0, const u8* __restrict__ W1,
        const u8* __restrict__ seqbP,
        const float* __restrict__ b0, const float* __restrict__ b1,
        u8* __restrict__ a00, u8* __restrict__ a01,
        u8* __restrict__ a10, u8* __restrict__ a11,
        float* __restrict__ sqo, unsigned* __restrict__ bar) {
    __shared__ uint4 w1lds[8192];          // 128 KiB W1 slice
    __shared__ float part[16 * 16 * PSTR]; // 18.4 KiB
    const int jt = blockIdx.x, tid = threadIdx.x;
    const int wave = tid >> 6, l = tid & 63;
    const int gp = wave >> 3, ke = wave & 7;   // gate-pair, k-eighth
    const int la = l & 15, kg = l >> 4;
    const int tIdx = jt * 2 + gp;
    {
        const uint4* src = (const uint4*)(W1 + (size_t)jt * 131072);
        for (int i = tid; i < 8192; i += 1024) w1lds[i] = src[i];
    }
    // pin this wave's W0 fragments: kc2 = ke*8 .. ke*8+7
    l64x2 b0pin[8];
    {
        const u8* Bb = W0 + ((size_t)(tIdx * 64 + ke * 8) * 64 + l) * 16;
#pragma unroll
        for (int i = 0; i < 8; ++i) b0pin[i] = *(const l64x2*)(Bb + (size_t)i * 1024);
    }
    // registers: cell state + biases
    float cr0 = 0.f, cr1 = 0.f;
    float bi0 = 0, bf0 = 0, bg0 = 0, bo0 = 0, bi1 = 0, bf1 = 0, bg1 = 0, bo1 = 0;
    if (tid < 128) {
        int j = jt * 8 + (tid & 7);
        bi0 = b0[j]; bf0 = b0[FDIM + j]; bg0 = b0[2 * FDIM + j]; bo0 = b0[3 * FDIM + j];
        bi1 = b1[j]; bf1 = b1[FDIM + j]; bg1 = b1[2 * FDIM + j]; bo1 = b1[3 * FDIM + j];
    }
    __syncthreads();

    u8* a0arr[2] = {a00, a01};
    u8* a1arr[2] = {a10, a11};
    unsigned* bs = bar;
    const l64x2* bb1 = (const l64x2*)w1lds + ((size_t)(gp * 64 + ke * 8) * 64 + l);
    const f32x4 z = {0.f, 0.f, 0.f, 0.f};

    auto l0_phase = [&](const u8* xsrc, const u8* A0, u8* hA, u8* hB) {
        long fa[8], fb[8];
        const u8* base = ((ke < 4) ? xsrc : A0) + (size_t)(ke * 16) * 512 + (size_t)l * 8;
        loadA8_async(base, fa); loadA8_async(base + 4096, fb);
        vm_wait0();
        f32x4 qa = z, qb = z;
        mma8r(fa, b0pin, qa, qb);
        mma8r(fb, b0pin + 4, qa, qb);
        store_part(part, wave, kg, la, qa + qb);
        __syncthreads();
        cell_tail(jt, tid, part, bi0, bf0, bg0, bo0, cr0, hA, hB, nullptr);
    };
    auto l1_phase = [&](const u8* A1, u8* hA, u8* hB, float* slot) {
        long fa[8], fb[8];
        const u8* base = A1 + (size_t)(ke * 16) * 512 + (size_t)l * 8;
        loadA8_async(base, fa); loadA8_async(base + 4096, fb);
        vm_wait0();
        f32x4 qa = z, qb = z;
        mma8l(fa, bb1, qa, qb);
        mma8l(fb, bb1 + 4 * 64, qa, qb);
        store_part(part, wave, kg, la, qa + qb);
        __syncthreads();
        cell_tail(jt, tid, part, bi1, bf1, bg1, bo1, cr1, hA, hB, slot);
    };

    // stage 0: L0[0] (h-half zeros)
    l0_phase(seqbP, a00, a01, a10);
    grid_bar(bs); bs += BARSTRIDE;

    // fwd stages s=0..30: L0[s+1] + L1[s]; all 32 loads issued as ONE cluster
    for (int s = 0; s <= 30; ++s) {
        int bp = s & 1;
        const u8* A0 = a0arr[1 - bp];
        const u8* xs = seqbP + (size_t)(s + 1) * 32768;
        const u8* A1 = a1arr[bp];
        long f0a[8], f0b[8], f1a[8], f1b[8];
        const u8* base0 = ((ke < 4) ? xs : A0) + (size_t)(ke * 16) * 512 + (size_t)l * 8;
        const u8* base1 = A1 + (size_t)(ke * 16) * 512 + (size_t)l * 8;
        loadA8_async(base0, f0a); loadA8_async(base0 + 4096, f0b);
        loadA8_async(base1, f1a); loadA8_async(base1 + 4096, f1b);
        vm_wait0();
        f32x4 q0a = z, q0b = z, q1a = z, q1b = z;
        mma8r(f0a, b0pin, q0a, q0b);
        mma8r(f0b, b0pin + 4, q0a, q0b);
        mma8l(f1a, bb1, q1a, q1b);
        mma8l(f1b, bb1 + 4 * 64, q1a, q1b);
        store_part(part, wave, kg, la, q0a + q0b);
        __syncthreads();
        cell_tail(jt, tid, part, bi0, bf0, bg0, bo0, cr0, a0arr[bp], a1arr[1 - bp], nullptr);
        __syncthreads();
        store_part(part, wave, kg, la, q1a + q1b);
        __syncthreads();
        cell_tail(jt, tid, part, bi1, bf1, bg1, bo1, cr1, a1arr[1 - bp], a0arr[1 - bp], nullptr);
        grid_bar(bs); bs += BARSTRIDE;
    }
    // stage: L1[31] -> first recorded output
    l1_phase(a1arr[1], a1arr[0], a0arr[0], sqo);
    grid_bar(bs); bs += BARSTRIDE;
    // AR region s=32..62
    for (int s = 32; s < 63; ++s) {
        int bp = s & 1;
        l0_phase(a0arr[bp], a0arr[bp], a0arr[1 - bp], a1arr[bp]);
        grid_bar(bs); bs += BARSTRIDE;
        l1_phase(a1arr[bp], a1arr[1 - bp], a0arr[1 - bp],
                 sqo + (size_t)(s - 31) * NB * FDIM);
        if (s != 62) { grid_bar(bs); bs += BARSTRIDE; }
    }
}

// copy latent -> out[:, :, 0:32, :]
__global__ void copy_lat(const float* __restrict__ latent, float* __restrict__ out) {
    size_t i = (size_t)blockIdx.x * blockDim.x + threadIdx.x;
    if (i >= (size_t)1048576) return;
    size_t blk = i >> 8;
    size_t within = i & 255;
    float4 v = ((const float4*)latent)[i];
    ((float4*)out)[blk * 512 + within] = v;
}

// gen half: out[n][c][32+t][h] = sum_cb seq_out[t][n][h*64+cb]*w_out[c][cb] + b_out[c]
__global__ __launch_bounds__(256) void gen_out(const float* __restrict__ seq_out,
                        const float* __restrict__ w_out, const float* __restrict__ b_out,
                        float* __restrict__ out) {
    __shared__ float row[32 * 65];
    int b = blockIdx.x; int n = b >> 5, t = b & 31;
    const float* src = seq_out + ((size_t)t * NB + n) * FDIM;
    for (int i = threadIdx.x; i < FDIM; i += 256)
        row[(i >> 6) * 65 + (i & 63)] = src[i];
    __syncthreads();
    for (int it = 0; it < 32; ++it) {
        int o = it * 256 + threadIdx.x;
        int c = o >> 5, h = o & 31;
        float acc = b_out[c];
#pragma unroll
        for (int cb = 0; cb < CBD; ++cb) acc += row[h * 65 + cb] * w_out[c * CBD + cb];
        out[(((size_t)n * CDIM + c) * 64 + 32 + t) * HGT + h] = acc;
    }
}

extern "C" void kernel_launch(void* const* d_in, const int* in_sizes, int n_in,
                              void* d_out, int out_size, void* d_ws, size_t ws_size,
                              hipStream_t stream) {
    const float* latent = (const float*)d_in[0];
    const float* w_in   = (const float*)d_in[1];
    const float* b_in   = (const float*)d_in[2];
    const float* w_ih0  = (const float*)d_in[3];
    const float* w_hh0  = (const float*)d_in[4];
    const float* b_ih0  = (const float*)d_in[5];
    const float* b_hh0  = (const float*)d_in[6];
    const float* w_ih1  = (const float*)d_in[7];
    const float* w_hh1  = (const float*)d_in[8];
    const float* b_ih1  = (const float*)d_in[9];
    const float* b_hh1  = (const float*)d_in[10];
    const float* w_out  = (const float*)d_in[11];
    const float* b_out  = (const float*)d_in[12];
    float* out = (float*)d_out;
    char* ws = (char*)d_ws;

    size_t off = 0;
    u8*    W0   = (u8*)(ws + off); off += (size_t)512 * 65536;             // 32 MiB
    u8*    W1   = (u8*)(ws + off); off += (size_t)512 * 65536;             // 32 MiB
    u8*    seqbP= (u8*)(ws + off); off += (size_t)WSEQ * 32768;            // 1 MiB
    float* sqo  = (float*)(ws + off); off += (size_t)WSEQ * NB * FDIM * 4; // 4 MiB
    char*  zbase = ws + off;
    u8* a00 = (u8*)(ws + off); off += 65536;
    u8* a01 = (u8*)(ws + off); off += 65536;
    u8* a10 = (u8*)(ws + off); off += 65536;
    u8* a11 = (u8*)(ws + off); off += 65536;
    unsigned* bar = (unsigned*)(ws + off); off += (size_t)96 * BARSTRIDE * 4; // 204 KiB
    size_t zbytes = (size_t)(ws + off - zbase);
    float* b0 = (float*)(ws + off); off += (size_t)GDIM * 4;
    float* b1 = (float*)(ws + off); off += (size_t)GDIM * 4;

    if (ws_size < off) {
        hipMemsetAsync(d_out, 0, (size_t)out_size * 4, stream);
        return;
    }

    hipMemsetAsync(zbase, 0, zbytes, stream);
    pack_w<<<1024, 256, 0, stream>>>(w_ih0, w_hh0, w_ih1, w_hh1, W0, W1);
    bias_k<<<64, 256, 0, stream>>>(b_ih0, b_hh0, b_ih1, b_hh1, b0, b1);
    conv_in<<<512, 256, 0, stream>>>(latent, w_in, b_in, seqbP);
    recurrence<<<256, 1024, 0, stream>>>(W0, W1, seqbP, b0, b1,
                                         a00, a01, a10, a11, sqo, bar);
    copy_lat<<<4096, 256, 0, stream>>>(latent, out);
    gen_out<<<512, 256, 0, stream>>>(sqo, w_out, b_out, out);
}

// Round 11
// 1040.613 us; speedup vs baseline: 1.0207x; 1.0159x over previous
//
#include <hip/hip_runtime.h>
#include <hip/hip_bf16.h>

#define NB   16      // batch
#define FDIM 2048    // lstm hidden
#define GDIM 8192    // 4*FDIM gates
#define WSEQ 32      // seq len
#define CDIM 256
#define CBD  64
#define HGT  32

#define BARSTRIDE 544  // u32 per stage: 16 group lines + 1 root line, 128B apart
#define AGENTSC __HIP_MEMORY_SCOPE_AGENT

typedef float f32x4 __attribute__((ext_vector_type(4)));
typedef long  l64x2 __attribute__((ext_vector_type(2)));
typedef _Float16 f16x4 __attribute__((ext_vector_type(4)));
typedef unsigned char u8;

__device__ __forceinline__ float sigf(float x) { return 1.f / (1.f + __expf(-x)); }

__device__ __forceinline__ u8 f32_to_fp8(float f) {
    int w = __builtin_amdgcn_cvt_pk_fp8_f32(f, f, 0, 0);
    return (u8)(w & 0xff);
}

// ---------------------------------------------------------------------------
// Coalesced weight pack -> fp8 e4m3 (layout as R5-R10), 4 rows in flight.
// W[tile][kc2][lane][16B]; bytes0-7 = frag kc=2kc2, 8-15 = kc=2kc2+1;
// frag byte i of (kc,lane): k = kc*32+(lane>>4)*8+i, col = lane&15.
// ---------------------------------------------------------------------------
__global__ __launch_bounds__(256) void pack_w(
        const float* __restrict__ wih0, const float* __restrict__ whh0,
        const float* __restrict__ wih1, const float* __restrict__ whh1,
        u8* __restrict__ W0, u8* __restrict__ W1) {
    __shared__ u8 FW[16][4112];   // [c][k], +16 pad
    int b = blockIdx.x;           // 0..1023
    int mat = b >> 9, tile = b & 511;
    const float* wih = mat ? wih1 : wih0;
    const float* whh = mat ? whh1 : whh0;
    int p = tile & 1, jt = tile >> 1;
    int tid = threadIdx.x;
    for (int it = 0; it < 32; it += 4) {   // 2 src halves x 16 rows, 4-deep ILP
        float4 f[4][2];
#pragma unroll
        for (int r = 0; r < 4; ++r) {
            int c = (it + r) & 15, srcsel = (it + r) >> 4;
            int gate = p * 2 + (c >> 3);
            int rr = gate * FDIM + jt * 8 + (c & 7);
            const float* s = (srcsel ? whh : wih) + (size_t)rr * FDIM + tid * 8;
            f[r][0] = *(const float4*)(s);
            f[r][1] = *(const float4*)(s + 4);
        }
#pragma unroll
        for (int r = 0; r < 4; ++r) {
            int c = (it + r) & 15, srcsel = (it + r) >> 4;
            int w0 = __builtin_amdgcn_cvt_pk_fp8_f32(f[r][0].x, f[r][0].y, 0, 0);
            w0     = __builtin_amdgcn_cvt_pk_fp8_f32(f[r][0].z, f[r][0].w, w0, 1);
            int w1 = __builtin_amdgcn_cvt_pk_fp8_f32(f[r][1].x, f[r][1].y, 0, 0);
            w1     = __builtin_amdgcn_cvt_pk_fp8_f32(f[r][1].z, f[r][1].w, w1, 1);
            *(int2*)&FW[c][srcsel * 2048 + tid * 8] = make_int2(w0, w1);
        }
    }
    __syncthreads();
    u8* base = (mat ? W1 : W0) + (size_t)tile * 65536;
#pragma unroll
    for (int w = 0; w < 16; ++w) {
        int q = w * 256 + tid;            // kc2*64 + lane
        int kc2 = q >> 6, lane = q & 63;
        int c = lane & 15, kg = lane >> 4;
        l64x2 v;
        v.x = *(const long*)&FW[c][kc2 * 64 + kg * 8];
        v.y = *(const long*)&FW[c][kc2 * 64 + 32 + kg * 8];
        *(l64x2*)(base + (size_t)q * 16) = v;
    }
}

__global__ void bias_k(const float* __restrict__ bih0, const float* __restrict__ bhh0,
                       const float* __restrict__ bih1, const float* __restrict__ bhh1,
                       float* __restrict__ b0, float* __restrict__ b1) {
    int i = blockIdx.x * blockDim.x + threadIdx.x;
    if (i < GDIM)            b0[i] = bih0[i] + bhh0[i];
    else if (i < 2 * GDIM) { int j = i - GDIM; b1[j] = bih1[j] + bhh1[j]; }
}

// ---------------------------------------------------------------------------
// 1x1 conv-in; emit seq in PACKED A-fragment layout:
//   seqbP[t] : [64 kc][64 lane][8B], byte i of (kc,lane): k = kc*32+(lane>>4)*8+i
// ---------------------------------------------------------------------------
__global__ __launch_bounds__(256) void conv_in(const float* __restrict__ latent,
                        const float* __restrict__ w_in, const float* __restrict__ b_in,
                        u8* __restrict__ seqbP) {
    __shared__ float lat[CDIM * HGT]; // [c][h] 32 KiB
    __shared__ float hv[FDIM];        // 8 KiB
    int b = blockIdx.x; int n = b >> 5; int t = b & 31;
    int tid = threadIdx.x;
    for (int i = 0; i < 32; ++i) {
        int flat = i * 256 + tid;         // c*32+h
        int c = flat >> 5, h = flat & 31;
        lat[flat] = latent[(((size_t)n * CDIM + c) * WSEQ + t) * HGT + h];
    }
    __syncthreads();
    int cb = tid & 63;
    int hb = tid >> 6;
    float acc[8];
#pragma unroll
    for (int k = 0; k < 8; ++k) acc[k] = b_in[cb];
    for (int c = 0; c < CDIM; ++c) {
        float wv = w_in[cb * CDIM + c];
#pragma unroll
        for (int k = 0; k < 8; ++k) acc[k] += lat[c * HGT + (hb + k * 4)] * wv;
    }
#pragma unroll
    for (int k = 0; k < 8; ++k) hv[k * 256 + tid] = acc[k];   // hv[f], f = h*64+cb
    __syncthreads();
    union { u8 by[8]; long l; } pk;
#pragma unroll
    for (int i = 0; i < 8; ++i) pk.by[i] = f32_to_fp8(hv[tid * 8 + i]);
    *(long*)(seqbP + (size_t)t * 32768 + (tid >> 2) * 512 + (tid & 3) * 128 + n * 8) = pk.l;
}

// ---------------------------------------------------------------------------
// Async 8x8B load clusters (chunk stride 512B), no intervening waits.
// sc1 = agent-coherent (L2-bypass, reads L3) for cross-block activations.
// ---------------------------------------------------------------------------
__device__ __forceinline__ void load8_sc1(const u8* p, long* f) {
    asm volatile("global_load_dwordx2 %0, %1, off sc1"             : "=v"(f[0]) : "v"(p));
    asm volatile("global_load_dwordx2 %0, %1, off offset:512 sc1"  : "=v"(f[1]) : "v"(p));
    asm volatile("global_load_dwordx2 %0, %1, off offset:1024 sc1" : "=v"(f[2]) : "v"(p));
    asm volatile("global_load_dwordx2 %0, %1, off offset:1536 sc1" : "=v"(f[3]) : "v"(p));
    asm volatile("global_load_dwordx2 %0, %1, off offset:2048 sc1" : "=v"(f[4]) : "v"(p));
    asm volatile("global_load_dwordx2 %0, %1, off offset:2560 sc1" : "=v"(f[5]) : "v"(p));
    asm volatile("global_load_dwordx2 %0, %1, off offset:3072 sc1" : "=v"(f[6]) : "v"(p));
    asm volatile("global_load_dwordx2 %0, %1, off offset:3584 sc1" : "=v"(f[7]) : "v"(p));
}
__device__ __forceinline__ void load8_plain(const u8* p, long* f) {
    asm volatile("global_load_dwordx2 %0, %1, off"             : "=v"(f[0]) : "v"(p));
    asm volatile("global_load_dwordx2 %0, %1, off offset:512"  : "=v"(f[1]) : "v"(p));
    asm volatile("global_load_dwordx2 %0, %1, off offset:1024" : "=v"(f[2]) : "v"(p));
    asm volatile("global_load_dwordx2 %0, %1, off offset:1536" : "=v"(f[3]) : "v"(p));
    asm volatile("global_load_dwordx2 %0, %1, off offset:2048" : "=v"(f[4]) : "v"(p));
    asm volatile("global_load_dwordx2 %0, %1, off offset:2560" : "=v"(f[5]) : "v"(p));
    asm volatile("global_load_dwordx2 %0, %1, off offset:3072" : "=v"(f[6]) : "v"(p));
    asm volatile("global_load_dwordx2 %0, %1, off offset:3584" : "=v"(f[7]) : "v"(p));
}

__device__ __forceinline__ void vm_wait0() {
    asm volatile("s_waitcnt vmcnt(0)" ::: "memory");
    __builtin_amdgcn_sched_barrier(0);   // keep MFMAs from hoisting above the wait
}

// lgkm-only block sync: LDS-ordered barrier that does NOT drain vmcnt,
// so in-flight global loads survive across it.
__device__ __forceinline__ void sync_lds() {
    asm volatile("s_waitcnt lgkmcnt(0)" ::: "memory");
    __builtin_amdgcn_s_barrier();
    asm volatile("" ::: "memory");
}

__device__ __forceinline__ f32x4 mfma8(long a, long b, f32x4 acc) {
    return __builtin_amdgcn_mfma_f32_16x16x32_fp8_fp8(a, b, acc, 0, 0, 0);
}

// 8 chunks against register-pinned B (b[i] = kc2 pair i)
__device__ __forceinline__ void mma8_reg(const long* f, const l64x2* b, f32x4& acc) {
#pragma unroll
    for (int i = 0; i < 4; ++i) {
        acc = mfma8(f[2 * i],     b[i].x, acc);
        acc = mfma8(f[2 * i + 1], b[i].y, acc);
    }
}
// 8 chunks against LDS B (stride 64 l64x2 per kc2)
__device__ __forceinline__ void mma8_lds(const long* f, const l64x2* bb, f32x4& acc) {
#pragma unroll
    for (int i = 0; i < 4; ++i) {
        l64x2 bl = bb[(size_t)i * 64];
        acc = mfma8(f[2 * i],     bl.x, acc);
        acc = mfma8(f[2 * i + 1], bl.y, acc);
    }
}

// fp16 partials: part16[t][w][col(la)][rowpad 20]; one 8B ds_write per frag.
__device__ __forceinline__ void store_frag(_Float16* part16, int t, int w,
                                           int kg, int la, f32x4 acc) {
    f16x4 h;
#pragma unroll
    for (int q = 0; q < 4; ++q) h[q] = (_Float16)acc[q];
    *(f16x4*)&part16[(((t * 16 + w) * 16) + la) * 20 + kg * 4] = h;
}

// LSTM cell tail: 16-deep partial reduce (fp16->f32), cell in regs, sc1 h out.
__device__ __forceinline__ void cell_tail16(const _Float16* part16, int jt, int tid,
        float bi, float bf, float bg, float bo, float& cr,
        u8* hA, u8* hB, float* seqSlot) {
    if (tid < 128) {
        int m = tid >> 3, jj = tid & 7;
        float gi = 0.f, gf = 0.f, gg = 0.f, go = 0.f;
#pragma unroll
        for (int w2 = 0; w2 < 16; ++w2) {
            int i0 = (w2 * 16 + jj) * 20 + m;
            gi += (float)part16[i0];
            gf += (float)part16[i0 + 160];
            gg += (float)part16[i0 + 5120];
            go += (float)part16[i0 + 5280];
        }
        float cn = sigf(gf + bf) * cr + sigf(gi + bi) * tanhf(gg + bg);
        float h  = sigf(go + bo) * tanhf(cn);
        cr = cn;
        u8 hb = f32_to_fp8(h);
        int pos = (jt >> 2) * 512 + (jt & 3) * 128 + tid;
        __hip_atomic_store(hA + 32768 + pos, hb, __ATOMIC_RELAXED, AGENTSC);
        __hip_atomic_store(hB + pos,         hb, __ATOMIC_RELAXED, AGENTSC);
        if (seqSlot) seqSlot[m * FDIM + jt * 8 + jj] = h;
    }
}

// Grid barrier (R8 protocol): RELEASE arrivals (16 groups x 16 + root, 128B
// isolated, fresh per stage), RELAXED polls, NO fence — coherence carried by
// sc1 stores/loads. Entry __syncthreads drains each wave's sc1 h-stores.
__device__ __forceinline__ void grid_bar(unsigned* base) {
    __syncthreads();
    if (threadIdx.x == 0) {
        unsigned* loc  = base + (blockIdx.x & 15) * 32;
        unsigned* root = base + 512;
        unsigned prev = __hip_atomic_fetch_add(loc, 1u, __ATOMIC_RELEASE, AGENTSC);
        if (prev == 15u)
            __hip_atomic_fetch_add(root, 1u, __ATOMIC_RELEASE, AGENTSC);
        int guard = 0;
        while (__hip_atomic_load(root, __ATOMIC_RELAXED, AGENTSC) < 16u
               && ++guard < (1 << 24))
            __builtin_amdgcn_s_sleep(1);
    }
    __syncthreads();
}

// ---------------------------------------------------------------------------
// Persistent recurrence. 256 blocks x 1024 thr (1 block/CU). Block jt owns
// features jt*8..jt*8+7 for all 4 gates. DEDUP wave map: wave w handles K
// chunks w*8..w*8+7 for BOTH gate-pair tiles (each chunk loaded once/block).
// W1 slice in LDS; W0 slice pinned in regs; fp16 partials. AR region: waves
// 8-15 issue next phase's (old) h-half loads at this phase's start, so each
// phase exposes exactly one fresh L3 round trip.
// ---------------------------------------------------------------------------
__global__ __launch_bounds__(1024, 4) void recurrence(
        const u8* __restrict__ W0, const u8* __restrict__ W1,
        const u8* __restrict__ seqbP,
        const float* __restrict__ b0, const float* __restrict__ b1,
        u8* __restrict__ a00, u8* __restrict__ a01,
        u8* __restrict__ a10, u8* __restrict__ a11,
        float* __restrict__ sqo, unsigned* __restrict__ bar) {
    __shared__ uint4 w1lds[8192];                  // 128 KiB W1 slice
    __shared__ _Float16 part16[2 * 16 * 16 * 20];  // 20 KiB fp16 partials
    const int jt = blockIdx.x, tid = threadIdx.x;
    const int w = tid >> 6, l = tid & 63;
    const int la = l & 15, kg = l >> 4;
    {
        const uint4* src = (const uint4*)(W1 + (size_t)jt * 131072);
        for (int i = tid; i < 8192; i += 1024) w1lds[i] = src[i];
    }
    // pin W0: tiles jt*2+t, kc2 = w*4..w*4+3  -> b0pin[t*4+i]
    l64x2 b0pin[8];
#pragma unroll
    for (int t = 0; t < 2; ++t)
#pragma unroll
        for (int i = 0; i < 4; ++i)
            b0pin[t * 4 + i] = *(const l64x2*)(W0 +
                ((size_t)((jt * 2 + t) * 64 + w * 4 + i) * 64 + l) * 16);
    float cr0 = 0.f, cr1 = 0.f;
    float bi0 = 0, bf0 = 0, bg0 = 0, bo0 = 0, bi1 = 0, bf1 = 0, bg1 = 0, bo1 = 0;
    if (tid < 128) {
        int j = jt * 8 + (tid & 7);
        bi0 = b0[j]; bf0 = b0[FDIM + j]; bg0 = b0[2 * FDIM + j]; bo0 = b0[3 * FDIM + j];
        bi1 = b1[j]; bf1 = b1[FDIM + j]; bg1 = b1[2 * FDIM + j]; bo1 = b1[3 * FDIM + j];
    }
    __syncthreads();

    u8* a0arr[2] = {a00, a01};
    u8* a1arr[2] = {a10, a11};
    unsigned* bs = bar;
    const l64x2* bbA = (const l64x2*)w1lds + ((size_t)(w * 4) * 64 + l);          // W1 tile0
    const l64x2* bbB = bbA + (size_t)64 * 64;                                      // W1 tile1
    const f32x4 z = {0.f, 0.f, 0.f, 0.f};
    const size_t wl = (size_t)w * 4096 + (size_t)l * 8;  // this wave's chunk window

    long fhA[8], fhB[8];

    // ---- stage 0: L0[0] (x from seqbP, h-half zeros) ----
    {
        if (w < 8) load8_plain(seqbP + wl, fhA);
        else       load8_sc1(a00 + wl, fhA);
        vm_wait0();
        f32x4 t0 = z, t1 = z;
        mma8_reg(fhA, b0pin, t0); mma8_reg(fhA, b0pin + 4, t1);
        store_frag(part16, 0, w, kg, la, t0);
        store_frag(part16, 1, w, kg, la, t1);
        sync_lds();
        cell_tail16(part16, jt, tid, bi0, bf0, bg0, bo0, cr0, a01, a10, nullptr);
        grid_bar(bs); bs += BARSTRIDE;
    }
    // ---- fwd pair stages s=0..30: L0[s+1] + L1[s] ----
    for (int s = 0; s <= 30; ++s) {
        int bp = s & 1;
        const u8* A0 = a0arr[1 - bp];
        const u8* xs = seqbP + (size_t)(s + 1) * 32768;
        const u8* A1 = a1arr[bp];
        long f1[8];
        if (w < 8) load8_plain(xs + wl, fhA);   // static x
        else       load8_sc1(A0 + wl, fhA);     // fresh h0[s]
        load8_sc1(A1 + wl, f1);                 // fresh [h0[s] | h1[s-1]]
        vm_wait0();
        f32x4 q00 = z, q01 = z, q10 = z, q11 = z;
        mma8_reg(fhA, b0pin, q00); mma8_reg(fhA, b0pin + 4, q01);
        mma8_lds(f1, bbA, q10);    mma8_lds(f1, bbB, q11);
        store_frag(part16, 0, w, kg, la, q00);
        store_frag(part16, 1, w, kg, la, q01);
        sync_lds();
        cell_tail16(part16, jt, tid, bi0, bf0, bg0, bo0, cr0,
                    a0arr[bp], a1arr[1 - bp], nullptr);
        sync_lds();
        store_frag(part16, 0, w, kg, la, q10);
        store_frag(part16, 1, w, kg, la, q11);
        sync_lds();
        cell_tail16(part16, jt, tid, bi1, bf1, bg1, bo1, cr1,
                    a1arr[1 - bp], a0arr[1 - bp], nullptr);
        grid_bar(bs); bs += BARSTRIDE;
    }
    // ---- L1[31]: records first output; pre-issue AR L0[32]'s h-half ----
    {
        const u8* A1 = a1arr[1];
        load8_sc1(A1 + wl, fhB);                         // both halves fresh
        vm_wait0();
        f32x4 t0 = z, t1 = z;
        mma8_lds(fhB, bbA, t0); mma8_lds(fhB, bbB, t1);
        if (w >= 8) load8_sc1(a0arr[0] + wl, fhA);       // h0[31] (visible)
        store_frag(part16, 0, w, kg, la, t0);
        store_frag(part16, 1, w, kg, la, t1);
        sync_lds();
        cell_tail16(part16, jt, tid, bi1, bf1, bg1, bo1, cr1,
                    a1arr[0], a0arr[0], sqo);
        grid_bar(bs); bs += BARSTRIDE;
    }
    // ---- AR region s=32..62 ----
    for (int s = 32; s < 63; ++s) {
        int bp = s & 1;
        // L0[s]: fhA ready for w>=8 (pre-issued); w<8 load fresh x = h1[s-1]
        {
            if (w < 8) load8_sc1(a0arr[bp] + wl, fhA);
            else       load8_sc1(a1arr[bp] + wl, fhB);   // old h1[s-1] for L1[s]
            vm_wait0();
            f32x4 t0 = z, t1 = z;
            mma8_reg(fhA, b0pin, t0); mma8_reg(fhA, b0pin + 4, t1);
            store_frag(part16, 0, w, kg, la, t0);
            store_frag(part16, 1, w, kg, la, t1);
            sync_lds();
            cell_tail16(part16, jt, tid, bi0, bf0, bg0, bo0, cr0,
                        a0arr[1 - bp], a1arr[bp], nullptr);
            grid_bar(bs); bs += BARSTRIDE;
        }
        // L1[s]: fhB ready for w>=8; w<8 load fresh x = h0[s]
        {
            if (w < 8)              load8_sc1(a1arr[bp] + wl, fhB);
            else if (s != 62)       load8_sc1(a0arr[1 - bp] + wl, fhA); // old h0[s] for L0[s+1]
            vm_wait0();
            f32x4 t0 = z, t1 = z;
            mma8_lds(fhB, bbA, t0); mma8_lds(fhB, bbB, t1);
            store_frag(part16, 0, w, kg, la, t0);
            store_frag(part16, 1, w, kg, la, t1);
            sync_lds();
            cell_tail16(part16, jt, tid, bi1, bf1, bg1, bo1, cr1,
                        a1arr[1 - bp], a0arr[1 - bp],
                        sqo + (size_t)(s - 31) * NB * FDIM);
            if (s != 62) { grid_bar(bs); bs += BARSTRIDE; }
        }
    }
}

// copy latent -> out[:, :, 0:32, :]
__global__ void copy_lat(const float* __restrict__ latent, float* __restrict__ out) {
    size_t i = (size_t)blockIdx.x * blockDim.x + threadIdx.x;
    if (i >= (size_t)1048576) return;
    size_t blk = i >> 8;
    size_t within = i & 255;
    float4 v = ((const float4*)latent)[i];
    ((float4*)out)[blk * 512 + within] = v;
}

// gen half: out[n][c][32+t][h] = sum_cb seq_out[t][n][h*64+cb]*w_out[c][cb] + b_out[c]
__global__ __launch_bounds__(256) void gen_out(const float* __restrict__ seq_out,
                        const float* __restrict__ w_out, const float* __restrict__ b_out,
                        float* __restrict__ out) {
    __shared__ float row[32 * 65];
    int b = blockIdx.x; int n = b >> 5, t = b & 31;
    const float* src = seq_out + ((size_t)t * NB + n) * FDIM;
    for (int i = threadIdx.x; i < FDIM; i += 256)
        row[(i >> 6) * 65 + (i & 63)] = src[i];
    __syncthreads();
    for (int it = 0; it < 32; ++it) {
        int o = it * 256 + threadIdx.x;
        int c = o >> 5, h = o & 31;
        float acc = b_out[c];
#pragma unroll
        for (int cb = 0; cb < CBD; ++cb) acc += row[h * 65 + cb] * w_out[c * CBD + cb];
        out[(((size_t)n * CDIM + c) * 64 + 32 + t) * HGT + h] = acc;
    }
}

extern "C" void kernel_launch(void* const* d_in, const int* in_sizes, int n_in,
                              void* d_out, int out_size, void* d_ws, size_t ws_size,
                              hipStream_t stream) {
    const float* latent = (const float*)d_in[0];
    const float* w_in   = (const float*)d_in[1];
    const float* b_in   = (const float*)d_in[2];
    const float* w_ih0  = (const float*)d_in[3];
    const float* w_hh0  = (const float*)d_in[4];
    const float* b_ih0  = (const float*)d_in[5];
    const float* b_hh0  = (const float*)d_in[6];
    const float* w_ih1  = (const float*)d_in[7];
    const float* w_hh1  = (const float*)d_in[8];
    const float* b_ih1  = (const float*)d_in[9];
    const float* b_hh1  = (const float*)d_in[10];
    const float* w_out  = (const float*)d_in[11];
    const float* b_out  = (const float*)d_in[12];
    float* out = (float*)d_out;
    char* ws = (char*)d_ws;

    size_t off = 0;
    u8*    W0   = (u8*)(ws + off); off += (size_t)512 * 65536;             // 32 MiB
    u8*    W1   = (u8*)(ws + off); off += (size_t)512 * 65536;             // 32 MiB
    u8*    seqbP= (u8*)(ws + off); off += (size_t)WSEQ * 32768;            // 1 MiB
    float* sqo  = (float*)(ws + off); off += (size_t)WSEQ * NB * FDIM * 4; // 4 MiB
    char*  zbase = ws + off;
    u8* a00 = (u8*)(ws + off); off += 65536;
    u8* a01 = (u8*)(ws + off); off += 65536;
    u8* a10 = (u8*)(ws + off); off += 65536;
    u8* a11 = (u8*)(ws + off); off += 65536;
    unsigned* bar = (unsigned*)(ws + off); off += (size_t)96 * BARSTRIDE * 4; // 204 KiB
    size_t zbytes = (size_t)(ws + off - zbase);
    float* b0 = (float*)(ws + off); off += (size_t)GDIM * 4;
    float* b1 = (float*)(ws + off); off += (size_t)GDIM * 4;

    if (ws_size < off) {
        hipMemsetAsync(d_out, 0, (size_t)out_size * 4, stream);
        return;
    }

    hipMemsetAsync(zbase, 0, zbytes, stream);
    pack_w<<<1024, 256, 0, stream>>>(w_ih0, w_hh0, w_ih1, w_hh1, W0, W1);
    bias_k<<<64, 256, 0, stream>>>(b_ih0, b_hh0, b_ih1, b_hh1, b0, b1);
    conv_in<<<512, 256, 0, stream>>>(latent, w_in, b_in, seqbP);
    recurrence<<<256, 1024, 0, stream>>>(W0, W1, seqbP, b0, b1,
                                         a00, a01, a10, a11, sqo, bar);
    copy_lat<<<4096, 256, 0, stream>>>(latent, out);
    gen_out<<<512, 256, 0, stream>>>(sqo, w_out, b_out, out);
}

// Round 12
// 767.865 us; speedup vs baseline: 1.3833x; 1.3552x over previous
//
#include <hip/hip_runtime.h>
#include <hip/hip_bf16.h>

#define NB   16      // batch
#define FDIM 2048    // lstm hidden
#define GDIM 8192    // 4*FDIM gates
#define WSEQ 32      // seq len
#define CDIM 256
#define CBD  64
#define HGT  32

#define AGENTSC __HIP_MEMORY_SCOPE_AGENT

typedef float f32x4 __attribute__((ext_vector_type(4)));
typedef long  l64x2 __attribute__((ext_vector_type(2)));
typedef _Float16 f16x4 __attribute__((ext_vector_type(4)));
typedef unsigned char u8;

__device__ __forceinline__ float sigf(float x) { return 1.f / (1.f + __expf(-x)); }

__device__ __forceinline__ u8 f32_to_fp8(float f) {
    int w = __builtin_amdgcn_cvt_pk_fp8_f32(f, f, 0, 0);
    return (u8)(w & 0xff);
}

// ---------------------------------------------------------------------------
// Coalesced weight pack -> fp8 e4m3 (layout as R5-R11), 4 rows in flight.
// W[tile][kc2][lane][16B]; bytes0-7 = frag kc=2kc2, 8-15 = kc=2kc2+1;
// frag byte i of (kc,lane): k = kc*32+(lane>>4)*8+i, col = lane&15.
// ---------------------------------------------------------------------------
__global__ __launch_bounds__(256) void pack_w(
        const float* __restrict__ wih0, const float* __restrict__ whh0,
        const float* __restrict__ wih1, const float* __restrict__ whh1,
        u8* __restrict__ W0, u8* __restrict__ W1) {
    __shared__ u8 FW[16][4112];   // [c][k], +16 pad
    int b = blockIdx.x;           // 0..1023
    int mat = b >> 9, tile = b & 511;
    const float* wih = mat ? wih1 : wih0;
    const float* whh = mat ? whh1 : whh0;
    int p = tile & 1, jt = tile >> 1;
    int tid = threadIdx.x;
    for (int it = 0; it < 32; it += 4) {   // 2 src halves x 16 rows, 4-deep ILP
        float4 f[4][2];
#pragma unroll
        for (int r = 0; r < 4; ++r) {
            int c = (it + r) & 15, srcsel = (it + r) >> 4;
            int gate = p * 2 + (c >> 3);
            int rr = gate * FDIM + jt * 8 + (c & 7);
            const float* s = (srcsel ? whh : wih) + (size_t)rr * FDIM + tid * 8;
            f[r][0] = *(const float4*)(s);
            f[r][1] = *(const float4*)(s + 4);
        }
#pragma unroll
        for (int r = 0; r < 4; ++r) {
            int c = (it + r) & 15, srcsel = (it + r) >> 4;
            int w0 = __builtin_amdgcn_cvt_pk_fp8_f32(f[r][0].x, f[r][0].y, 0, 0);
            w0     = __builtin_amdgcn_cvt_pk_fp8_f32(f[r][0].z, f[r][0].w, w0, 1);
            int w1 = __builtin_amdgcn_cvt_pk_fp8_f32(f[r][1].x, f[r][1].y, 0, 0);
            w1     = __builtin_amdgcn_cvt_pk_fp8_f32(f[r][1].z, f[r][1].w, w1, 1);
            *(int2*)&FW[c][srcsel * 2048 + tid * 8] = make_int2(w0, w1);
        }
    }
    __syncthreads();
    u8* base = (mat ? W1 : W0) + (size_t)tile * 65536;
#pragma unroll
    for (int w = 0; w < 16; ++w) {
        int q = w * 256 + tid;            // kc2*64 + lane
        int kc2 = q >> 6, lane = q & 63;
        int c = lane & 15, kg = lane >> 4;
        l64x2 v;
        v.x = *(const long*)&FW[c][kc2 * 64 + kg * 8];
        v.y = *(const long*)&FW[c][kc2 * 64 + 32 + kg * 8];
        *(l64x2*)(base + (size_t)q * 16) = v;
    }
}

__global__ void bias_k(const float* __restrict__ bih0, const float* __restrict__ bhh0,
                       const float* __restrict__ bih1, const float* __restrict__ bhh1,
                       float* __restrict__ b0, float* __restrict__ b1) {
    int i = blockIdx.x * blockDim.x + threadIdx.x;
    if (i < GDIM)            b0[i] = bih0[i] + bhh0[i];
    else if (i < 2 * GDIM) { int j = i - GDIM; b1[j] = bih1[j] + bhh1[j]; }
}

// ---------------------------------------------------------------------------
// 1x1 conv-in; emit seq in PACKED A-fragment layout:
//   seqbP[t] : [64 kc][64 lane][8B], byte i of (kc,lane): k = kc*32+(lane>>4)*8+i
// ---------------------------------------------------------------------------
__global__ __launch_bounds__(256) void conv_in(const float* __restrict__ latent,
                        const float* __restrict__ w_in, const float* __restrict__ b_in,
                        u8* __restrict__ seqbP) {
    __shared__ float lat[CDIM * HGT]; // [c][h] 32 KiB
    __shared__ float hv[FDIM];        // 8 KiB
    int b = blockIdx.x; int n = b >> 5; int t = b & 31;
    int tid = threadIdx.x;
    for (int i = 0; i < 32; ++i) {
        int flat = i * 256 + tid;         // c*32+h
        int c = flat >> 5, h = flat & 31;
        lat[flat] = latent[(((size_t)n * CDIM + c) * WSEQ + t) * HGT + h];
    }
    __syncthreads();
    int cb = tid & 63;
    int hb = tid >> 6;
    float acc[8];
#pragma unroll
    for (int k = 0; k < 8; ++k) acc[k] = b_in[cb];
    for (int c = 0; c < CDIM; ++c) {
        float wv = w_in[cb * CDIM + c];
#pragma unroll
        for (int k = 0; k < 8; ++k) acc[k] += lat[c * HGT + (hb + k * 4)] * wv;
    }
#pragma unroll
    for (int k = 0; k < 8; ++k) hv[k * 256 + tid] = acc[k];   // hv[f], f = h*64+cb
    __syncthreads();
    union { u8 by[8]; long l; } pk;
#pragma unroll
    for (int i = 0; i < 8; ++i) pk.by[i] = f32_to_fp8(hv[tid * 8 + i]);
    *(long*)(seqbP + (size_t)t * 32768 + (tid >> 2) * 512 + (tid & 3) * 128 + n * 8) = pk.l;
}

// ---------------------------------------------------------------------------
// Async 8x8B PLAIN (L2-cached) load cluster, chunk stride 512B, no waits.
// Safe because every activation buffer address is written exactly once
// (fresh per stage) before its single consuming stage -> no stale L2 lines.
// ---------------------------------------------------------------------------
__device__ __forceinline__ void load8_plain(const u8* p, long* f) {
    asm volatile("global_load_dwordx2 %0, %1, off"             : "=v"(f[0]) : "v"(p));
    asm volatile("global_load_dwordx2 %0, %1, off offset:512"  : "=v"(f[1]) : "v"(p));
    asm volatile("global_load_dwordx2 %0, %1, off offset:1024" : "=v"(f[2]) : "v"(p));
    asm volatile("global_load_dwordx2 %0, %1, off offset:1536" : "=v"(f[3]) : "v"(p));
    asm volatile("global_load_dwordx2 %0, %1, off offset:2048" : "=v"(f[4]) : "v"(p));
    asm volatile("global_load_dwordx2 %0, %1, off offset:2560" : "=v"(f[5]) : "v"(p));
    asm volatile("global_load_dwordx2 %0, %1, off offset:3072" : "=v"(f[6]) : "v"(p));
    asm volatile("global_load_dwordx2 %0, %1, off offset:3584" : "=v"(f[7]) : "v"(p));
}

__device__ __forceinline__ void vm_wait0() {
    asm volatile("s_waitcnt vmcnt(0)" ::: "memory");
    __builtin_amdgcn_sched_barrier(0);   // keep MFMAs from hoisting above the wait
}

// lgkm-only block sync (does NOT drain vmcnt)
__device__ __forceinline__ void sync_lds() {
    asm volatile("s_waitcnt lgkmcnt(0)" ::: "memory");
    __builtin_amdgcn_s_barrier();
    asm volatile("" ::: "memory");
}

__device__ __forceinline__ f32x4 mfma8(long a, long b, f32x4 acc) {
    return __builtin_amdgcn_mfma_f32_16x16x32_fp8_fp8(a, b, acc, 0, 0, 0);
}

__device__ __forceinline__ void mma8_reg(const long* f, const l64x2* b, f32x4& acc) {
#pragma unroll
    for (int i = 0; i < 4; ++i) {
        acc = mfma8(f[2 * i],     b[i].x, acc);
        acc = mfma8(f[2 * i + 1], b[i].y, acc);
    }
}
__device__ __forceinline__ void mma8_lds(const long* f, const l64x2* bb, f32x4& acc) {
#pragma unroll
    for (int i = 0; i < 4; ++i) {
        l64x2 bl = bb[(size_t)i * 64];
        acc = mfma8(f[2 * i],     bl.x, acc);
        acc = mfma8(f[2 * i + 1], bl.y, acc);
    }
}

// fp16 partials: part16[t][w][col(la)][m pad20]; one 8B ds_write per frag.
__device__ __forceinline__ void store_frag(_Float16* part16, int t, int w,
                                           int kg, int la, f32x4 acc) {
    f16x4 h;
#pragma unroll
    for (int q = 0; q < 4; ++q) h[q] = (_Float16)acc[q];
    *(f16x4*)&part16[(((t * 16 + w) * 16) + la) * 20 + kg * 4] = h;
}

// LSTM cell tail: 16-deep fp16 partial reduce; cell state in regs; h -> two
// fresh 32KiB buffers via sc1 byte stores (straight to L3, never dirty L2).
__device__ __forceinline__ void cell_tail16(const _Float16* part16, int jt, int tid,
        float bi, float bf, float bg, float bo, float& cr,
        u8* oA, u8* oB, float* seqSlot) {
    if (tid < 128) {
        int m = tid >> 3, jj = tid & 7;
        float gi = 0.f, gf = 0.f, gg = 0.f, go = 0.f;
#pragma unroll
        for (int w2 = 0; w2 < 16; ++w2) {
            int i0 = (w2 * 16 + jj) * 20 + m;
            gi += (float)part16[i0];
            gf += (float)part16[i0 + 160];
            gg += (float)part16[i0 + 5120];
            go += (float)part16[i0 + 5280];
        }
        float cn = sigf(gf + bf) * cr + sigf(gi + bi) * tanhf(gg + bg);
        float h  = sigf(go + bo) * tanhf(cn);
        cr = cn;
        u8 hb = f32_to_fp8(h);
        int pos = (jt >> 2) * 512 + (jt & 3) * 128 + tid;
        __hip_atomic_store(oA + pos, hb, __ATOMIC_RELAXED, AGENTSC);
        __hip_atomic_store(oB + pos, hb, __ATOMIC_RELAXED, AGENTSC);
        if (seqSlot)
            __hip_atomic_store(seqSlot + m * FDIM + jt * 8 + jj, h,
                               __ATOMIC_RELAXED, AGENTSC);
    }
}

// ---------------------------------------------------------------------------
// Store-slot grid barrier: per-stage arr[k][256]. Arrival = ONE sc1 store
// (no RMW convoy). Wave 0 polls all 256 slots (1 dwordx4 per lane). Entry
// __syncthreads drains every wave's sc1 h-stores (compiler emits vmcnt(0)).
// ---------------------------------------------------------------------------
__device__ __forceinline__ void grid_bar(unsigned* slots) {
    __syncthreads();
    if (threadIdx.x < 64) {
        if (threadIdx.x == 0) {
            unsigned one = 1u;
            const unsigned* p = slots + blockIdx.x;
            asm volatile("global_store_dword %0, %1, off sc1"
                         :: "v"(p), "v"(one) : "memory");
        }
        const uint4* q = (const uint4*)slots + threadIdx.x;
        int guard = 0;
        while (++guard < (1 << 22)) {
            uint4 v;
            asm volatile("global_load_dwordx4 %0, %1, off sc1"
                         : "=v"(v) : "v"(q) : "memory");
            asm volatile("s_waitcnt vmcnt(0)" ::: "memory");
            if (__all((v.x & v.y & v.z & v.w) != 0u)) break;
            __builtin_amdgcn_s_sleep(1);
        }
    }
    __syncthreads();
}

// ---------------------------------------------------------------------------
// Persistent recurrence. 256 blocks x 1024 thr (1 block/CU). Block jt owns
// features jt*8..jt*8+7 for all 4 gates. Dedup wave map: wave w covers K
// chunks w*8..w*8+7 for both gate-pair tiles. W1 slice in LDS; W0 slice in
// regs; biases + cell state in regs. Activations rotate through per-stage
// FRESH buffers: plain L2-cached reads, sc1 writes, no invalidation needed.
// ---------------------------------------------------------------------------
__global__ __launch_bounds__(1024, 4) void recurrence(
        const u8* __restrict__ W0, const u8* __restrict__ W1,
        const u8* __restrict__ seqbP,
        const float* __restrict__ b0, const float* __restrict__ b1,
        u8* __restrict__ h0A, u8* __restrict__ h0B,
        u8* __restrict__ h1A, u8* __restrict__ h1B,
        const u8* __restrict__ zb,
        float* __restrict__ sqo, unsigned* __restrict__ arr) {
    __shared__ uint4 w1lds[8192];                  // 128 KiB W1 slice
    __shared__ _Float16 part16[2 * 16 * 16 * 20];  // 20 KiB fp16 partials
    const int jt = blockIdx.x, tid = threadIdx.x;
    const int w = tid >> 6, l = tid & 63;
    const int la = l & 15, kg = l >> 4;
    {
        const uint4* src = (const uint4*)(W1 + (size_t)jt * 131072);
        for (int i = tid; i < 8192; i += 1024) w1lds[i] = src[i];
    }
    // pin W0: tiles jt*2+t, kc2 = w*4..w*4+3  -> b0pin[t*4+i]
    l64x2 b0pin[8];
#pragma unroll
    for (int t = 0; t < 2; ++t)
#pragma unroll
        for (int i = 0; i < 4; ++i)
            b0pin[t * 4 + i] = *(const l64x2*)(W0 +
                ((size_t)((jt * 2 + t) * 64 + w * 4 + i) * 64 + l) * 16);
    float cr0 = 0.f, cr1 = 0.f;
    float bi0 = 0, bf0 = 0, bg0 = 0, bo0 = 0, bi1 = 0, bf1 = 0, bg1 = 0, bo1 = 0;
    if (tid < 128) {
        int j = jt * 8 + (tid & 7);
        bi0 = b0[j]; bf0 = b0[FDIM + j]; bg0 = b0[2 * FDIM + j]; bo0 = b0[3 * FDIM + j];
        bi1 = b1[j]; bf1 = b1[FDIM + j]; bg1 = b1[2 * FDIM + j]; bo1 = b1[3 * FDIM + j];
    }
    __syncthreads();

    unsigned* bs = arr;
    const l64x2* bbA = (const l64x2*)w1lds + ((size_t)(w * 4) * 64 + l);
    const l64x2* bbB = bbA + (size_t)64 * 64;
    const f32x4 z = {0.f, 0.f, 0.f, 0.f};
    const size_t wl = (size_t)w * 4096 + (size_t)l * 8;        // waves 0-7 window
    const size_t wh = (size_t)(w - 8) * 4096 + (size_t)l * 8;  // waves 8-15 window
#define HB(arrp, s) ((arrp) + (size_t)(s) * 32768)

    auto l0_phase = [&](const u8* xp, const u8* hp, u8* oA, u8* oB) {
        long f[8];
        load8_plain((w < 8) ? xp + wl : hp + wh, f);
        vm_wait0();
        f32x4 t0 = z, t1 = z;
        mma8_reg(f, b0pin, t0); mma8_reg(f, b0pin + 4, t1);
        store_frag(part16, 0, w, kg, la, t0);
        store_frag(part16, 1, w, kg, la, t1);
        sync_lds();
        cell_tail16(part16, jt, tid, bi0, bf0, bg0, bo0, cr0, oA, oB, nullptr);
    };
    auto l1_phase = [&](const u8* p1, const u8* p2, u8* oA, u8* oB, float* slot) {
        long f[8];
        load8_plain((w < 8) ? p1 + wl : p2 + wh, f);
        vm_wait0();
        f32x4 t0 = z, t1 = z;
        mma8_lds(f, bbA, t0); mma8_lds(f, bbB, t1);
        store_frag(part16, 0, w, kg, la, t0);
        store_frag(part16, 1, w, kg, la, t1);
        sync_lds();
        cell_tail16(part16, jt, tid, bi1, bf1, bg1, bo1, cr1, oA, oB, slot);
    };

    // ---- stage 0: L0[0] (x = seqbP[0], h = zeros) ----
    l0_phase(seqbP, zb, HB(h0A, 0), HB(h0B, 0));
    grid_bar(bs); bs += 256;

    // ---- fwd pair stages s=0..30: L0[s+1] + L1[s] ----
    for (int s = 0; s <= 30; ++s) {
        long f0[8], f1[8];
        const u8* a0src = (w < 8) ? seqbP + (size_t)(s + 1) * 32768 + wl
                                  : HB(h0A, s) + wh;
        const u8* a1src = (w < 8) ? HB(h0B, s) + wl
                                  : (s == 0 ? zb + wh : HB(h1A, s - 1) + wh);
        load8_plain(a0src, f0);
        load8_plain(a1src, f1);
        vm_wait0();
        f32x4 q00 = z, q01 = z, q10 = z, q11 = z;
        mma8_reg(f0, b0pin, q00); mma8_reg(f0, b0pin + 4, q01);
        mma8_lds(f1, bbA, q10);   mma8_lds(f1, bbB, q11);
        store_frag(part16, 0, w, kg, la, q00);
        store_frag(part16, 1, w, kg, la, q01);
        sync_lds();
        cell_tail16(part16, jt, tid, bi0, bf0, bg0, bo0, cr0,
                    HB(h0A, s + 1), HB(h0B, s + 1), nullptr);
        sync_lds();
        store_frag(part16, 0, w, kg, la, q10);
        store_frag(part16, 1, w, kg, la, q11);
        sync_lds();
        cell_tail16(part16, jt, tid, bi1, bf1, bg1, bo1, cr1,
                    HB(h1A, s), HB(h1B, s), nullptr);
        grid_bar(bs); bs += 256;
    }
    // ---- L1[31]: first recorded output ----
    l1_phase(HB(h0B, 31), HB(h1A, 30), HB(h1A, 31), HB(h1B, 31), sqo);
    grid_bar(bs); bs += 256;
    // ---- AR region s=32..62 ----
    for (int s = 32; s < 63; ++s) {
        l0_phase(HB(h1B, s - 1), HB(h0A, s - 1), HB(h0A, s), HB(h0B, s));
        grid_bar(bs); bs += 256;
        l1_phase(HB(h0B, s), HB(h1A, s - 1), HB(h1A, s), HB(h1B, s),
                 sqo + (size_t)(s - 31) * NB * FDIM);
        if (s != 62) { grid_bar(bs); bs += 256; }
    }
#undef HB
}

// copy latent -> out[:, :, 0:32, :]
__global__ void copy_lat(const float* __restrict__ latent, float* __restrict__ out) {
    size_t i = (size_t)blockIdx.x * blockDim.x + threadIdx.x;
    if (i >= (size_t)1048576) return;
    size_t blk = i >> 8;
    size_t within = i & 255;
    float4 v = ((const float4*)latent)[i];
    ((float4*)out)[blk * 512 + within] = v;
}

// gen half: out[n][c][32+t][h] = sum_cb seq_out[t][n][h*64+cb]*w_out[c][cb] + b_out[c]
__global__ __launch_bounds__(256) void gen_out(const float* __restrict__ seq_out,
                        const float* __restrict__ w_out, const float* __restrict__ b_out,
                        float* __restrict__ out) {
    __shared__ float row[32 * 65];
    int b = blockIdx.x; int n = b >> 5, t = b & 31;
    const float* src = seq_out + ((size_t)t * NB + n) * FDIM;
    for (int i = threadIdx.x; i < FDIM; i += 256)
        row[(i >> 6) * 65 + (i & 63)] = src[i];
    __syncthreads();
    for (int it = 0; it < 32; ++it) {
        int o = it * 256 + threadIdx.x;
        int c = o >> 5, h = o & 31;
        float acc = b_out[c];
#pragma unroll
        for (int cb = 0; cb < CBD; ++cb) acc += row[h * 65 + cb] * w_out[c * CBD + cb];
        out[(((size_t)n * CDIM + c) * 64 + 32 + t) * HGT + h] = acc;
    }
}

extern "C" void kernel_launch(void* const* d_in, const int* in_sizes, int n_in,
                              void* d_out, int out_size, void* d_ws, size_t ws_size,
                              hipStream_t stream) {
    const float* latent = (const float*)d_in[0];
    const float* w_in   = (const float*)d_in[1];
    const float* b_in   = (const float*)d_in[2];
    const float* w_ih0  = (const float*)d_in[3];
    const float* w_hh0  = (const float*)d_in[4];
    const float* b_ih0  = (const float*)d_in[5];
    const float* b_hh0  = (const float*)d_in[6];
    const float* w_ih1  = (const float*)d_in[7];
    const float* w_hh1  = (const float*)d_in[8];
    const float* b_ih1  = (const float*)d_in[9];
    const float* b_hh1  = (const float*)d_in[10];
    const float* w_out  = (const float*)d_in[11];
    const float* b_out  = (const float*)d_in[12];
    float* out = (float*)d_out;
    char* ws = (char*)d_ws;

    size_t off = 0;
    u8*    W0   = (u8*)(ws + off); off += (size_t)512 * 65536;             // 32 MiB
    u8*    W1   = (u8*)(ws + off); off += (size_t)512 * 65536;             // 32 MiB
    u8*    seqbP= (u8*)(ws + off); off += (size_t)WSEQ * 32768;            // 1 MiB
    float* sqo  = (float*)(ws + off); off += (size_t)WSEQ * NB * FDIM * 4; // 4 MiB
    u8*    h0A  = (u8*)(ws + off); off += (size_t)64 * 32768;              // 2 MiB
    u8*    h0B  = (u8*)(ws + off); off += (size_t)64 * 32768;              // 2 MiB
    u8*    h1A  = (u8*)(ws + off); off += (size_t)64 * 32768;              // 2 MiB
    u8*    h1B  = (u8*)(ws + off); off += (size_t)64 * 32768;              // 2 MiB
    char*  zbase = ws + off;
    u8*    zb   = (u8*)(ws + off); off += 32768;                           // zeros
    unsigned* arr = (unsigned*)(ws + off); off += (size_t)94 * 1024;       // 94 KiB
    size_t zbytes = (size_t)(ws + off - zbase);
    float* b0 = (float*)(ws + off); off += (size_t)GDIM * 4;
    float* b1 = (float*)(ws + off); off += (size_t)GDIM * 4;

    if (ws_size < off) {
        hipMemsetAsync(d_out, 0, (size_t)out_size * 4, stream);
        return;
    }

    hipMemsetAsync(zbase, 0, zbytes, stream);
    pack_w<<<1024, 256, 0, stream>>>(w_ih0, w_hh0, w_ih1, w_hh1, W0, W1);
    bias_k<<<64, 256, 0, stream>>>(b_ih0, b_hh0, b_ih1, b_hh1, b0, b1);
    conv_in<<<512, 256, 0, stream>>>(latent, w_in, b_in, seqbP);
    recurrence<<<256, 1024, 0, stream>>>(W0, W1, seqbP, b0, b1,
                                         h0A, h0B, h1A, h1B, zb, sqo, arr);
    copy_lat<<<4096, 256, 0, stream>>>(latent, out);
    gen_out<<<512, 256, 0, stream>>>(sqo, w_out, b_out, out);
}